// Round 6
// baseline (709.527 us; speedup 1.0000x reference)
//
#include <hip/hip_runtime.h>
#include <cstdint>
#include <cstddef>

// ---------------------------------------------------------------------------
// SparseConv3DBlock: BN(inference)+SiLU -> gather(27 neighbors) -> implicit GEMM
// N=200000, F_IN=64, F_OUT=128, K=27.  bf16 MFMA path.
//   k1: y_bf16[N][64] = silu(bn(x))
//   k2: Wt_bf16[27][128][64] = transpose(W)
//   k3: BM=128, 8 waves. T14 async-STAGE, DEPTH-2: phase k global_loads A(k+2)
//       into alternate reg-set (compiler-tracked), MFMAs k, ds_writes the set
//       holding A(k+1) (loaded one full phase ago -> ~2 phases latency cover),
//       one __syncthreads per phase. XOR swizzle on ds_write. No s_idx LDS
//       (per-lane idx reads, L1-hot) -> 32 KB LDS -> 4 blocks/CU.
// ---------------------------------------------------------------------------

typedef __attribute__((ext_vector_type(8))) short short8;
typedef __attribute__((ext_vector_type(4))) float f32x4;

#define N_VOX 200000
#define F_IN 64
#define F_OUT 128
#define KOFF 27
#define BM 128

__device__ __forceinline__ short f2bf(float f) {
  unsigned u = __builtin_bit_cast(unsigned, f);
  u += 0x7fffu + ((u >> 16) & 1u);   // RNE
  return (short)(u >> 16);
}

// ---------------- Kernel 1: BN + SiLU + cast to bf16 ----------------------
__global__ __launch_bounds__(256) void bn_silu_kernel(
    const float* __restrict__ x, const float* __restrict__ gamma,
    const float* __restrict__ beta, const float* __restrict__ mean,
    const float* __restrict__ var, short* __restrict__ y) {
  __shared__ float s_scale[F_IN], s_bias[F_IN];
  int tid = threadIdx.x;
  if (tid < F_IN) {
    float s = gamma[tid] * rsqrtf(var[tid] + 1e-5f);
    s_scale[tid] = s;
    s_bias[tid] = beta[tid] - mean[tid] * s;
  }
  __syncthreads();
  size_t i = ((size_t)blockIdx.x * 256 + tid) * 8;   // 12.8M total, exact
  int f0 = (int)(i & (F_IN - 1));                    // multiple of 8
  float4 x0 = *(const float4*)(x + i);
  float4 x1 = *(const float4*)(x + i + 4);
  float v[8] = {x0.x, x0.y, x0.z, x0.w, x1.x, x1.y, x1.z, x1.w};
  short8 o;
#pragma unroll
  for (int j = 0; j < 8; ++j) {
    float t = v[j] * s_scale[f0 + j] + s_bias[f0 + j];
    float sg = 1.0f / (1.0f + __expf(-t));
    o[j] = f2bf(t * sg);
  }
  *(short8*)(y + i) = o;
}

// ---------------- Kernel 2: W[27][64][128] f32 -> Wt[27][128][64] bf16 ----
__global__ __launch_bounds__(256) void wprep_kernel(
    const float* __restrict__ W, short* __restrict__ Wt) {
  int tid = blockIdx.x * 256 + threadIdx.x;        // 27*128*8 = 27648 threads
  if (tid >= KOFF * F_OUT * 8) return;
  int k = tid >> 10;                               // /(128*8)
  int r = tid & 1023;
  int o = r >> 3;
  int f0 = (r & 7) * 8;
  short8 vv;
#pragma unroll
  for (int i = 0; i < 8; ++i)
    vv[i] = f2bf(W[((size_t)k * F_IN + f0 + i) * F_OUT + o]);
  *(short8*)(Wt + ((size_t)k * F_OUT + o) * F_IN + f0) = vv;
}

// ---------------- Kernel 3: depth-2 reg-staged gather + implicit GEMM -----
// BM=128 voxels/block, 512 threads = 8 waves. Wave w: rows 0..127 x cols
// [16w,16w+16): 8 row-tiles of 16x16, K=64 per k-offset (16 MFMA/phase).
// Phase k: load A(k+2)->ARNEXT, B(k+1)->BNEXT; MFMA(k) from buf[k&1];
// ds_write ARCUR (=A(k+1), loaded at phase k-1) -> buf[(k&1)^1]; sync.

__global__ __launch_bounds__(512, 8) void conv_mfma_kernel(
    const short* __restrict__ y,     // [N][64] bf16
    const short* __restrict__ Wt,    // [27][128][64] bf16
    const int* __restrict__ nidx,    // [N][27]
    float* __restrict__ out) {       // [N][128] f32
  __shared__ __align__(16) short Atile[2][BM * F_IN];   // 2 x 16 KB

  const int tid = threadIdx.x;
  const int wave = tid >> 6;         // 0..7
  const int lane = tid & 63;
  const int lhi = lane >> 4;         // 0..3
  const int llo = lane & 15;
  const int row0 = blockIdx.x * BM;

  // gather geometry: lane serves rows m0, m1 = m0+8, chunk c (16B units)
  const int m0 = wave * 16 + (lane >> 3);
  const int m1 = m0 + 8;
  const int c = lane & 7;
  // swizzled LDS byte offsets for ds_write (m1&7 == m0&7 so wr1 = wr0+1024)
  const int wr0 = m0 * 128 + ((c ^ (m0 & 7)) << 4);
  const int wr1 = wr0 + 1024;
  // per-lane idx streams (8 lanes share each address -> HW broadcast;
  // clamp tail rows to a valid row, stores are masked later)
  const int gr0 = (row0 + m0 < N_VOX) ? row0 + m0 : N_VOX - 1;
  const int gr1 = (row0 + m1 < N_VOX) ? row0 + m1 : N_VOX - 1;
  const int* ip0 = nidx + (size_t)gr0 * KOFF;
  const int* ip1 = nidx + (size_t)gr1 * KOFF;
  // B stream: wave's col slice, frag base
  const short* wtp = Wt + (size_t)(wave * 16 + llo) * F_IN + lhi * 8;

  f32x4 acc[8] = {};
  short8 b0[2], b1[2];               // B double buffer
  short8 arA0, arA1, arB0, arB1;     // A reg sets (depth-2 staging)

  // ---- prologue: A(0) -> buf0 (immediate); A(1) -> set A; B(0) ----
  {
    const int g0 = ip0[0], g1 = ip1[0];
    short8 t0 = *(const short8*)(y + (size_t)g0 * F_IN + c * 8);
    short8 t1 = *(const short8*)(y + (size_t)g1 * F_IN + c * 8);
    const int h0 = ip0[1], h1 = ip1[1];
    arA0 = *(const short8*)(y + (size_t)h0 * F_IN + c * 8);
    arA1 = *(const short8*)(y + (size_t)h1 * F_IN + c * 8);
    b0[0] = *(const short8*)(wtp);
    b0[1] = *(const short8*)(wtp + 32);
    *(short8*)((char*)Atile[0] + wr0) = t0;
    *(short8*)((char*)Atile[0] + wr1) = t1;
  }
  __syncthreads();

  // Phase K: ARCUR holds A(K+1); ARNEXT receives A(K+2).
#define CONV_BODY(K, BUF, BCUR, BNEXT, AC0, AC1, AN0, AN1)                     \
  {                                                                            \
    if ((K) + 2 < KOFF) {                                                      \
      const int g0 = ip0[(K) + 2], g1 = ip1[(K) + 2];                          \
      AN0 = *(const short8*)(y + (size_t)g0 * F_IN + c * 8);                   \
      AN1 = *(const short8*)(y + (size_t)g1 * F_IN + c * 8);                   \
    }                                                                          \
    if ((K) + 1 < KOFF) {                                                      \
      (BNEXT)[0] = *(const short8*)(wtp + (size_t)((K) + 1) * 8192);           \
      (BNEXT)[1] = *(const short8*)(wtp + (size_t)((K) + 1) * 8192 + 32);      \
    }                                                                          \
    __builtin_amdgcn_sched_barrier(0); /* loads issue before MFMA region */    \
    _Pragma("unroll")                                                          \
    for (int rt = 0; rt < 8; ++rt) {                                           \
      const int mm = rt * 16 + llo;                                            \
      const int base = mm * 128 + lhi * 16;                                    \
      const int swz = (mm & 7) << 4;                                           \
      short8 a0 = *(const short8*)((const char*)Atile[BUF] + (base ^ swz));    \
      short8 a1 =                                                              \
          *(const short8*)((const char*)Atile[BUF] + ((base + 64) ^ swz));     \
      acc[rt] = __builtin_amdgcn_mfma_f32_16x16x32_bf16(a0, (BCUR)[0],         \
                                                        acc[rt], 0, 0, 0);     \
      acc[rt] = __builtin_amdgcn_mfma_f32_16x16x32_bf16(a1, (BCUR)[1],         \
                                                        acc[rt], 0, 0, 0);     \
    }                                                                          \
    __builtin_amdgcn_sched_barrier(0); /* keep ds_writes after MFMAs */        \
    if ((K) + 1 < KOFF) {                                                      \
      *(short8*)((char*)Atile[(BUF) ^ 1] + wr0) = AC0;                         \
      *(short8*)((char*)Atile[(BUF) ^ 1] + wr1) = AC1;                         \
    }                                                                          \
    __syncthreads();                                                           \
  }

  for (int k = 0; k < KOFF - 1; k += 2) {        // k = 0,2,...,24
    CONV_BODY(k, 0, b0, b1, arA0, arA1, arB0, arB1);
    CONV_BODY(k + 1, 1, b1, b0, arB0, arB1, arA0, arA1);
  }
  CONV_BODY(KOFF - 1, 0, b0, b1, arA0, arA1, arB0, arB1);   // k = 26
#undef CONV_BODY

  // ---- epilogue: C/D layout col=lane&15, row=(lane>>4)*4+j ----
#pragma unroll
  for (int rt = 0; rt < 8; ++rt) {
    const int col = wave * 16 + llo;
    const int rbase = row0 + rt * 16 + lhi * 4;
#pragma unroll
    for (int j = 0; j < 4; ++j) {
      const int row = rbase + j;
      if (row < N_VOX) out[(size_t)row * F_OUT + col] = acc[rt][j];
    }
  }
}

// ---------------------------------------------------------------------------
extern "C" void kernel_launch(void* const* d_in, const int* in_sizes, int n_in,
                              void* d_out, int out_size, void* d_ws, size_t ws_size,
                              hipStream_t stream) {
  const float* x     = (const float*)d_in[0];
  const float* gamma = (const float*)d_in[1];
  const float* beta  = (const float*)d_in[2];
  const float* rmean = (const float*)d_in[3];
  const float* rvar  = (const float*)d_in[4];
  const float* W     = (const float*)d_in[5];
  const int*   nidx  = (const int*)d_in[6];
  float* out = (float*)d_out;

  // workspace layout
  short* y_bf16  = (short*)d_ws;                                      // 25.6 MB
  short* Wt_bf16 = (short*)((char*)d_ws + (size_t)N_VOX * F_IN * 2);  // 442 KB

  bn_silu_kernel<<<(N_VOX * F_IN) / (256 * 8), 256, 0, stream>>>(
      x, gamma, beta, rmean, rvar, y_bf16);

  wprep_kernel<<<(KOFF * F_OUT * 8 + 255) / 256, 256, 0, stream>>>(W, Wt_bf16);

  conv_mfma_kernel<<<(N_VOX + BM - 1) / BM, 512, 0, stream>>>(
      y_bf16, Wt_bf16, nidx, out);
}

// Round 7
// 179.934 us; speedup vs baseline: 3.9433x; 3.9433x over previous
//
#include <hip/hip_runtime.h>
#include <cstdint>
#include <cstddef>

// ---------------------------------------------------------------------------
// SparseConv3DBlock: BN(inference)+SiLU -> gather(27 neighbors) -> implicit GEMM
// N=200000, F_IN=64, F_OUT=128, K=27.  bf16 MFMA path.
//   k1: y_bf16[N][64] = silu(bn(x))
//   k2: Wt_bf16[27][128][64] = transpose(W)
//   k3: BM=128, 8 waves. T14 async-STAGE, DEPTH-2: phase k global_loads A(k+2)
//       into alternate reg-set (compiler-tracked), MFMAs k, ds_writes the set
//       holding A(k+1) (loaded one full phase ago -> ~2 phases latency cover),
//       one __syncthreads per phase. XOR swizzle on ds_write. No s_idx LDS.
//   Round-6 lesson: __launch_bounds__(512,8) spilled (VGPR forced to 32,
//   FETCH 306MB->1.8GB scratch traffic). Keep (512,4): depth-2 needs ~60 VGPR.
// ---------------------------------------------------------------------------

typedef __attribute__((ext_vector_type(8))) short short8;
typedef __attribute__((ext_vector_type(4))) float f32x4;

#define N_VOX 200000
#define F_IN 64
#define F_OUT 128
#define KOFF 27
#define BM 128

__device__ __forceinline__ short f2bf(float f) {
  unsigned u = __builtin_bit_cast(unsigned, f);
  u += 0x7fffu + ((u >> 16) & 1u);   // RNE
  return (short)(u >> 16);
}

// ---------------- Kernel 1: BN + SiLU + cast to bf16 ----------------------
__global__ __launch_bounds__(256) void bn_silu_kernel(
    const float* __restrict__ x, const float* __restrict__ gamma,
    const float* __restrict__ beta, const float* __restrict__ mean,
    const float* __restrict__ var, short* __restrict__ y) {
  __shared__ float s_scale[F_IN], s_bias[F_IN];
  int tid = threadIdx.x;
  if (tid < F_IN) {
    float s = gamma[tid] * rsqrtf(var[tid] + 1e-5f);
    s_scale[tid] = s;
    s_bias[tid] = beta[tid] - mean[tid] * s;
  }
  __syncthreads();
  size_t i = ((size_t)blockIdx.x * 256 + tid) * 8;   // 12.8M total, exact
  int f0 = (int)(i & (F_IN - 1));                    // multiple of 8
  float4 x0 = *(const float4*)(x + i);
  float4 x1 = *(const float4*)(x + i + 4);
  float v[8] = {x0.x, x0.y, x0.z, x0.w, x1.x, x1.y, x1.z, x1.w};
  short8 o;
#pragma unroll
  for (int j = 0; j < 8; ++j) {
    float t = v[j] * s_scale[f0 + j] + s_bias[f0 + j];
    float sg = 1.0f / (1.0f + __expf(-t));
    o[j] = f2bf(t * sg);
  }
  *(short8*)(y + i) = o;
}

// ---------------- Kernel 2: W[27][64][128] f32 -> Wt[27][128][64] bf16 ----
__global__ __launch_bounds__(256) void wprep_kernel(
    const float* __restrict__ W, short* __restrict__ Wt) {
  int tid = blockIdx.x * 256 + threadIdx.x;        // 27*128*8 = 27648 threads
  if (tid >= KOFF * F_OUT * 8) return;
  int k = tid >> 10;                               // /(128*8)
  int r = tid & 1023;
  int o = r >> 3;
  int f0 = (r & 7) * 8;
  short8 vv;
#pragma unroll
  for (int i = 0; i < 8; ++i)
    vv[i] = f2bf(W[((size_t)k * F_IN + f0 + i) * F_OUT + o]);
  *(short8*)(Wt + ((size_t)k * F_OUT + o) * F_IN + f0) = vv;
}

// ---------------- Kernel 3: depth-2 reg-staged gather + implicit GEMM -----
// BM=128 voxels/block, 512 threads = 8 waves. Wave w: rows 0..127 x cols
// [16w,16w+16): 8 row-tiles of 16x16, K=64 per k-offset (16 MFMA/phase).
// Phase k: load A(k+2)->ARNEXT, B(k+1)->BNEXT; MFMA(k) from buf[k&1];
// ds_write ARCUR (=A(k+1), loaded one phase ago) -> buf[(k&1)^1]; sync.

__global__ __launch_bounds__(512, 4) void conv_mfma_kernel(
    const short* __restrict__ y,     // [N][64] bf16
    const short* __restrict__ Wt,    // [27][128][64] bf16
    const int* __restrict__ nidx,    // [N][27]
    float* __restrict__ out) {       // [N][128] f32
  __shared__ __align__(16) short Atile[2][BM * F_IN];   // 2 x 16 KB

  const int tid = threadIdx.x;
  const int wave = tid >> 6;         // 0..7
  const int lane = tid & 63;
  const int lhi = lane >> 4;         // 0..3
  const int llo = lane & 15;
  const int row0 = blockIdx.x * BM;

  // gather geometry: lane serves rows m0, m1 = m0+8, chunk c (16B units)
  const int m0 = wave * 16 + (lane >> 3);
  const int m1 = m0 + 8;
  const int c = lane & 7;
  // swizzled LDS byte offsets for ds_write (m1&7 == m0&7 so wr1 = wr0+1024)
  const int wr0 = m0 * 128 + ((c ^ (m0 & 7)) << 4);
  const int wr1 = wr0 + 1024;
  // per-lane idx streams (8 lanes share each address -> HW broadcast;
  // clamp tail rows to a valid row, stores are masked later)
  const int gr0 = (row0 + m0 < N_VOX) ? row0 + m0 : N_VOX - 1;
  const int gr1 = (row0 + m1 < N_VOX) ? row0 + m1 : N_VOX - 1;
  const int* ip0 = nidx + (size_t)gr0 * KOFF;
  const int* ip1 = nidx + (size_t)gr1 * KOFF;
  // B stream: wave's col slice, frag base
  const short* wtp = Wt + (size_t)(wave * 16 + llo) * F_IN + lhi * 8;

  f32x4 acc[8] = {};
  short8 b0[2], b1[2];               // B double buffer
  short8 arA0, arA1, arB0, arB1;     // A reg sets (depth-2 staging)

  // ---- prologue: A(0) -> buf0 (immediate); A(1) -> set A; B(0) ----
  {
    const int g0 = ip0[0], g1 = ip1[0];
    short8 t0 = *(const short8*)(y + (size_t)g0 * F_IN + c * 8);
    short8 t1 = *(const short8*)(y + (size_t)g1 * F_IN + c * 8);
    const int h0 = ip0[1], h1 = ip1[1];
    arA0 = *(const short8*)(y + (size_t)h0 * F_IN + c * 8);
    arA1 = *(const short8*)(y + (size_t)h1 * F_IN + c * 8);
    b0[0] = *(const short8*)(wtp);
    b0[1] = *(const short8*)(wtp + 32);
    *(short8*)((char*)Atile[0] + wr0) = t0;
    *(short8*)((char*)Atile[0] + wr1) = t1;
  }
  __syncthreads();

  // Phase K: ARCUR holds A(K+1); ARNEXT receives A(K+2).
#define CONV_BODY(K, BUF, BCUR, BNEXT, AC0, AC1, AN0, AN1)                     \
  {                                                                            \
    if ((K) + 2 < KOFF) {                                                      \
      const int g0 = ip0[(K) + 2], g1 = ip1[(K) + 2];                          \
      AN0 = *(const short8*)(y + (size_t)g0 * F_IN + c * 8);                   \
      AN1 = *(const short8*)(y + (size_t)g1 * F_IN + c * 8);                   \
    }                                                                          \
    if ((K) + 1 < KOFF) {                                                      \
      (BNEXT)[0] = *(const short8*)(wtp + (size_t)((K) + 1) * 8192);           \
      (BNEXT)[1] = *(const short8*)(wtp + (size_t)((K) + 1) * 8192 + 32);      \
    }                                                                          \
    __builtin_amdgcn_sched_barrier(0); /* loads issue before MFMA region */    \
    _Pragma("unroll")                                                          \
    for (int rt = 0; rt < 8; ++rt) {                                           \
      const int mm = rt * 16 + llo;                                            \
      const int base = mm * 128 + lhi * 16;                                    \
      const int swz = (mm & 7) << 4;                                           \
      short8 a0 = *(const short8*)((const char*)Atile[BUF] + (base ^ swz));    \
      short8 a1 =                                                              \
          *(const short8*)((const char*)Atile[BUF] + ((base + 64) ^ swz));     \
      acc[rt] = __builtin_amdgcn_mfma_f32_16x16x32_bf16(a0, (BCUR)[0],         \
                                                        acc[rt], 0, 0, 0);     \
      acc[rt] = __builtin_amdgcn_mfma_f32_16x16x32_bf16(a1, (BCUR)[1],         \
                                                        acc[rt], 0, 0, 0);     \
    }                                                                          \
    __builtin_amdgcn_sched_barrier(0); /* keep ds_writes after MFMAs */        \
    if ((K) + 1 < KOFF) {                                                      \
      *(short8*)((char*)Atile[(BUF) ^ 1] + wr0) = AC0;                         \
      *(short8*)((char*)Atile[(BUF) ^ 1] + wr1) = AC1;                         \
    }                                                                          \
    __syncthreads();                                                           \
  }

  for (int k = 0; k < KOFF - 1; k += 2) {        // k = 0,2,...,24
    CONV_BODY(k, 0, b0, b1, arA0, arA1, arB0, arB1);
    CONV_BODY(k + 1, 1, b1, b0, arB0, arB1, arA0, arA1);
  }
  CONV_BODY(KOFF - 1, 0, b0, b1, arA0, arA1, arB0, arB1);   // k = 26
#undef CONV_BODY

  // ---- epilogue: C/D layout col=lane&15, row=(lane>>4)*4+j ----
#pragma unroll
  for (int rt = 0; rt < 8; ++rt) {
    const int col = wave * 16 + llo;
    const int rbase = row0 + rt * 16 + lhi * 4;
#pragma unroll
    for (int j = 0; j < 4; ++j) {
      const int row = rbase + j;
      if (row < N_VOX) out[(size_t)row * F_OUT + col] = acc[rt][j];
    }
  }
}

// ---------------------------------------------------------------------------
extern "C" void kernel_launch(void* const* d_in, const int* in_sizes, int n_in,
                              void* d_out, int out_size, void* d_ws, size_t ws_size,
                              hipStream_t stream) {
  const float* x     = (const float*)d_in[0];
  const float* gamma = (const float*)d_in[1];
  const float* beta  = (const float*)d_in[2];
  const float* rmean = (const float*)d_in[3];
  const float* rvar  = (const float*)d_in[4];
  const float* W     = (const float*)d_in[5];
  const int*   nidx  = (const int*)d_in[6];
  float* out = (float*)d_out;

  // workspace layout
  short* y_bf16  = (short*)d_ws;                                      // 25.6 MB
  short* Wt_bf16 = (short*)((char*)d_ws + (size_t)N_VOX * F_IN * 2);  // 442 KB

  bn_silu_kernel<<<(N_VOX * F_IN) / (256 * 8), 256, 0, stream>>>(
      x, gamma, beta, rmean, rvar, y_bf16);

  wprep_kernel<<<(KOFF * F_OUT * 8 + 255) / 256, 256, 0, stream>>>(W, Wt_bf16);

  conv_mfma_kernel<<<(N_VOX + BM - 1) / BM, 512, 0, stream>>>(
      y_bf16, Wt_bf16, nidx, out);
}